// Round 6
// baseline (203.724 us; speedup 1.0000x reference)
//
#include <hip/hip_runtime.h>
#include <math.h>

typedef _Float16 f16x8 __attribute__((ext_vector_type(8)));
typedef float f32x4 __attribute__((ext_vector_type(4)));
typedef float f32x16 __attribute__((ext_vector_type(16)));

// Problem constants
#define NROWS 32768   // 8*4096 input rows
#define KEMB  8192    // codebook entries
// DIM = 64

#define DECAYF 0.99f
#define OMDF   0.01f

// d_out layout (floats), reference return order
#define OUT_Q    0          // quantized, 2097152
#define OUT_LOSS 2097152    // vq_loss, 1
#define OUT_IDX  2097153    // idx (as float), 32768
#define OUT_PERP 2129921    // perplexity, 1
#define OUT_NW   2129922    // new_weight, 524288
#define OUT_NCC  2654210    // new_cc, 8192
#define OUT_NWS  2662402    // new_ws, 524288

// d_ws layout (4-byte units)
#define WS_N      0
#define WS_ENT    1
#define WS_COUNTS 4                    // 8192 floats (argmin atomics; reused as loss partials)
#define WS_EMB    8196                 // 524288 floats (atomic)
#define WS_IDX    532484               // 32768 ints
#define WS_W2H    565252               // 8192 floats (= ||w||^2 / 2)
#define WS_WFRAG  573444               // 524288 f32 units = 2 MB f16 frag image
#define WS_ZERO_UNITS 532484           // scalars+counts+emb

__device__ __forceinline__ float sq_rn(float v) { return __fmul_rn(v, v); }

// numpy pairwise_sum order for 64 contiguous squared values
__device__ __forceinline__ float npsumsq64(const float* vbuf) {
  float a[8];
#pragma unroll
  for (int j = 0; j < 8; ++j) a[j] = sq_rn(vbuf[j]);
#pragma unroll
  for (int m = 1; m < 8; ++m)
#pragma unroll
    for (int j = 0; j < 8; ++j) a[j] = __fadd_rn(a[j], sq_rn(vbuf[m*8 + j]));
  return __fadd_rn(__fadd_rn(__fadd_rn(a[0],a[1]), __fadd_rn(a[2],a[3])),
                   __fadd_rn(__fadd_rn(a[4],a[5]), __fadd_rn(a[6],a[7])));
}

// split a float into (hi, lo) fp16 pair; hi+lo reproduces x to ~22 bits
__device__ __forceinline__ void split_f16(float x, _Float16& hi, _Float16& lo) {
  hi = (_Float16)x;
  float r = __fsub_rn(x, (float)hi);   // exact (Sterbenz)
  lo = (_Float16)r;
}

// prep: w2h[k] = 0.5*||w_k||^2 (numpy order), W -> 32x32x16 A-frag image.
// Panel p (0..255) = codes p*32..p*32+31. Frag f (0..7): f=t (0..3) hi for
// dims 16t..16t+15; f=4+t lo. Lane l of frag: code = l&31, k = (l>>5)*8+j.
// Image: wf[((p*8+f)*64 + l)*8 .. +8]; per-lane dwordx4 load IS an A-frag.
__global__ __launch_bounds__(256) void prep_kernel(const float* __restrict__ wg,
                                                   float* __restrict__ ws) {
  const int tid = blockIdx.x * 256 + threadIdx.x;
  if (tid < KEMB) {
    const float* src = wg + (size_t)tid * 64;
    float vbuf[64];
#pragma unroll
    for (int f = 0; f < 16; ++f) {
      float4 v = *(const float4*)(src + f*4);
      vbuf[f*4+0]=v.x; vbuf[f*4+1]=v.y; vbuf[f*4+2]=v.z; vbuf[f*4+3]=v.w;
    }
    ws[WS_W2H + tid] = __fmul_rn(0.5f, npsumsq64(vbuf));
  } else if (tid < KEMB + 65536) {
    const int u = tid - KEMB;            // granule: code K, dims g*8..g*8+7
    const int K = u >> 3, g = u & 7;
    const int p = K >> 5, c = K & 31;    // panel 0..255, code-in-panel
    const int tt = g >> 1, h = g & 1;    // k-slice 0..3, half 0..1
    const float* src = wg + (size_t)K*64 + g*8;
    float4 v0 = *(const float4*)src, v1 = *(const float4*)(src + 4);
    float vv[8] = {v0.x,v0.y,v0.z,v0.w,v1.x,v1.y,v1.z,v1.w};
    f16x8 hi, lo;
#pragma unroll
    for (int j = 0; j < 8; ++j) { _Float16 h2, l2; split_f16(vv[j], h2, l2); hi[j]=h2; lo[j]=l2; }
    _Float16* wf = (_Float16*)(ws + WS_WFRAG);
    *(f16x8*)&wf[((size_t)(p*8 + tt)*64 + h*32 + c)*8]     = hi;
    *(f16x8*)&wf[((size_t)(p*8 + 4 + tt)*64 + h*32 + c)*8] = lo;
  }
}

// load one panel's 8 W-frags + C-in (0.5||w||^2 arranged per C/D layout)
#define LOADW(H0,H1,H2,H3,L0,L1,L2,L3,CIN,WP,CP)                              \
  H0 = *(const f16x8*)(WP);                                                   \
  H1 = *(const f16x8*)(WP + 512);                                             \
  H2 = *(const f16x8*)(WP + 1024);                                            \
  H3 = *(const f16x8*)(WP + 1536);                                            \
  L0 = *(const f16x8*)(WP + 2048);                                            \
  L1 = *(const f16x8*)(WP + 2560);                                            \
  L2 = *(const f16x8*)(WP + 3072);                                            \
  L3 = *(const f16x8*)(WP + 3584);                                            \
  { float4 c0 = *(const float4*)(CP),      c1 = *(const float4*)(CP + 8);     \
    float4 c2 = *(const float4*)(CP + 16), c3 = *(const float4*)(CP + 24);    \
    CIN = (f32x16){c0.x,c0.y,c0.z,c0.w, c1.x,c1.y,c1.z,c1.w,                  \
                   c2.x,c2.y,c2.z,c2.w, c3.x,c3.y,c3.z,c3.w}; }               \
  WP += 32768; CP += 256;

// 24 MFMA per 32-code panel: Whi*Xhi(4) + Whi*Xlo(4) + Wlo*Xhi(4), 2 row-sets
// interleaved. C-in = 0.5||w||^2, X negated -> acc = dist proxy.
#define CLUSTER(H0,H1,H2,H3,L0,L1,L2,L3,CIN)                                   \
  __builtin_amdgcn_s_setprio(1);                                               \
  acc0 = __builtin_amdgcn_mfma_f32_32x32x16_f16(H0, xh00, CIN,  0,0,0);        \
  acc1 = __builtin_amdgcn_mfma_f32_32x32x16_f16(H0, xh10, CIN,  0,0,0);        \
  acc0 = __builtin_amdgcn_mfma_f32_32x32x16_f16(H1, xh01, acc0, 0,0,0);        \
  acc1 = __builtin_amdgcn_mfma_f32_32x32x16_f16(H1, xh11, acc1, 0,0,0);        \
  acc0 = __builtin_amdgcn_mfma_f32_32x32x16_f16(H2, xh02, acc0, 0,0,0);        \
  acc1 = __builtin_amdgcn_mfma_f32_32x32x16_f16(H2, xh12, acc1, 0,0,0);        \
  acc0 = __builtin_amdgcn_mfma_f32_32x32x16_f16(H3, xh03, acc0, 0,0,0);        \
  acc1 = __builtin_amdgcn_mfma_f32_32x32x16_f16(H3, xh13, acc1, 0,0,0);        \
  acc0 = __builtin_amdgcn_mfma_f32_32x32x16_f16(H0, xl00, acc0, 0,0,0);        \
  acc1 = __builtin_amdgcn_mfma_f32_32x32x16_f16(H0, xl10, acc1, 0,0,0);        \
  acc0 = __builtin_amdgcn_mfma_f32_32x32x16_f16(H1, xl01, acc0, 0,0,0);        \
  acc1 = __builtin_amdgcn_mfma_f32_32x32x16_f16(H1, xl11, acc1, 0,0,0);        \
  acc0 = __builtin_amdgcn_mfma_f32_32x32x16_f16(H2, xl02, acc0, 0,0,0);        \
  acc1 = __builtin_amdgcn_mfma_f32_32x32x16_f16(H2, xl12, acc1, 0,0,0);        \
  acc0 = __builtin_amdgcn_mfma_f32_32x32x16_f16(H3, xl03, acc0, 0,0,0);        \
  acc1 = __builtin_amdgcn_mfma_f32_32x32x16_f16(H3, xl13, acc1, 0,0,0);        \
  acc0 = __builtin_amdgcn_mfma_f32_32x32x16_f16(L0, xh00, acc0, 0,0,0);        \
  acc1 = __builtin_amdgcn_mfma_f32_32x32x16_f16(L0, xh10, acc1, 0,0,0);        \
  acc0 = __builtin_amdgcn_mfma_f32_32x32x16_f16(L1, xh01, acc0, 0,0,0);        \
  acc1 = __builtin_amdgcn_mfma_f32_32x32x16_f16(L1, xh11, acc1, 0,0,0);        \
  acc0 = __builtin_amdgcn_mfma_f32_32x32x16_f16(L2, xh02, acc0, 0,0,0);        \
  acc1 = __builtin_amdgcn_mfma_f32_32x32x16_f16(L2, xh12, acc1, 0,0,0);        \
  acc0 = __builtin_amdgcn_mfma_f32_32x32x16_f16(L3, xh03, acc0, 0,0,0);        \
  acc1 = __builtin_amdgcn_mfma_f32_32x32x16_f16(L3, xh13, acc1, 0,0,0);        \
  __builtin_amdgcn_s_setprio(0);

// in-register 16-code tournament for one row-set. C/D row r -> code offset
// crow(r) = (r&3)+8*(r>>2) (ascending in r), +4*hi folded into PB.
// Descending scan -> lowest r (= lowest code) wins ties, exactly.
#define TOURNP(ACC, S, PB)                                                     \
  {                                                                            \
    float pmA = fminf(fminf(fminf(ACC[0],ACC[1]),  fminf(ACC[2],ACC[3])),      \
                      fminf(fminf(ACC[4],ACC[5]),  fminf(ACC[6],ACC[7])));     \
    float pmB = fminf(fminf(fminf(ACC[8],ACC[9]),  fminf(ACC[10],ACC[11])),    \
                      fminf(fminf(ACC[12],ACC[13]),fminf(ACC[14],ACC[15])));   \
    const float pm = fminf(pmA, pmB);                                          \
    int kc = 27;                                                               \
    if (ACC[14] == pm) kc = 26;                                                \
    if (ACC[13] == pm) kc = 25;                                                \
    if (ACC[12] == pm) kc = 24;                                                \
    if (ACC[11] == pm) kc = 19;                                                \
    if (ACC[10] == pm) kc = 18;                                                \
    if (ACC[9]  == pm) kc = 17;                                                \
    if (ACC[8]  == pm) kc = 16;                                                \
    if (ACC[7]  == pm) kc = 11;                                                \
    if (ACC[6]  == pm) kc = 10;                                                \
    if (ACC[5]  == pm) kc = 9;                                                 \
    if (ACC[4]  == pm) kc = 8;                                                 \
    if (ACC[3]  == pm) kc = 3;                                                 \
    if (ACC[2]  == pm) kc = 2;                                                 \
    if (ACC[1]  == pm) kc = 1;                                                 \
    if (ACC[0]  == pm) kc = 0;                                                 \
    if (pm < bestd[S]) { bestd[S] = pm; bestk[S] = (PB) + kc; }                \
  }

// per-lane direct global X frag load (B operand): row = row0+S*32+(lane&31),
// dims T*16 + hi*8 .. +8, negated hi/lo split. No LDS staging at all.
#define LOADX(S, T, XH, XL)                                                    \
  {                                                                            \
    const float* src = xg + (size_t)(row0 + (S)*32 + r31)*64 + (T)*16 + hi*8;  \
    float4 v0 = *(const float4*)src, v1 = *(const float4*)(src + 4);           \
    float vv[8] = {v0.x,v0.y,v0.z,v0.w,v1.x,v1.y,v1.z,v1.w};                   \
    _Pragma("unroll")                                                          \
    for (int jj = 0; jj < 8; ++jj) {                                           \
      _Float16 h2, l2; split_f16(-vv[jj], h2, l2); XH[jj]=h2; XL[jj]=l2; }     \
  }

// argmin v13: 512 blocks x 256 threads (4 waves = code slices cg0..3),
// 64 rows/block. 32x32x16 MFMA: half the instruction count of 16x16x32 and
// the shape measured to sustain 62-86% matrix util at 2 waves/SIMD (m201/
// m233); 16x16x32 pinned at 44-50% across r0-r5 regardless of structure.
// Each lane owns one X-row per set -> tournament fully in-register; X frags
// loaded straight from global (L1-broadcast), LDS X-staging eliminated.
// waves_per_eu(2,2) pins the 256-reg budget (~215 live) at the grid-limited
// occupancy. W stream 2-deep double-buffered as in r5.
__global__ __attribute__((amdgpu_flat_work_group_size(256,256), amdgpu_waves_per_eu(2,2)))
void argmin_kernel(const float* __restrict__ xg,
                   float* __restrict__ out,
                   float* __restrict__ ws) {
  __shared__ float md[64*4];
  __shared__ int   mk[64*4];
  __shared__ int   bkL[64];

  const int t    = threadIdx.x;
  const int lane = t & 63, wv = t >> 6;     // wv 0..3
  const int r31 = lane & 31, hi = lane >> 5;
  const int hi4 = hi * 4;
  const int cg = wv;                        // code slice 0..3
  const int row0 = blockIdx.x * 64;
  const _Float16* __restrict__ wfrag = (const _Float16*)(ws + WS_WFRAG);
  const float* __restrict__ w2hg = ws + WS_W2H;

  // ---- X frags in registers: 2 sets x 4 k-slices, hi+lo (64 VGPRs) ----
  f16x8 xh00, xh01, xh02, xh03, xh10, xh11, xh12, xh13;
  f16x8 xl00, xl01, xl02, xl03, xl10, xl11, xl12, xl13;
  LOADX(0,0,xh00,xl00) LOADX(0,1,xh01,xl01) LOADX(0,2,xh02,xl02) LOADX(0,3,xh03,xl03)
  LOADX(1,0,xh10,xl10) LOADX(1,1,xh11,xl11) LOADX(1,2,xh12,xl12) LOADX(1,3,xh13,xl13)

  float bestd[2]; int bestk[2];
  bestd[0] = INFINITY; bestd[1] = INFINITY; bestk[0] = 0; bestk[1] = 0;

  // W panel stream: wave cg covers panels cg, cg+4, ..., cg+4*63.
  // setA = even-m panels (cg+8j), setB = odd-m (cg+4+8j).
  const _Float16* wpA = wfrag + (size_t)cg * 4096 + (size_t)lane * 8;
  const _Float16* wpB = wpA + 4*4096;
  const float*    cpA = w2hg + cg*32 + hi4;
  const float*    cpB = cpA + 4*32;

  f16x8 hA0,hA1,hA2,hA3,lA0,lA1,lA2,lA3;
  f16x8 hB0,hB1,hB2,hB3,lB0,lB1,lB2,lB3;
  f32x16 cinA, cinB;
  LOADW(hA0,hA1,hA2,hA3,lA0,lA1,lA2,lA3,cinA,wpA,cpA)
  LOADW(hB0,hB1,hB2,hB3,lB0,lB1,lB2,lB3,cinB,wpB,cpB)

  f32x16 acc0, acc1;
  int pbA = cg*32 + hi4;          // code base (incl. hi-half) for A panels
  int pbB = pbA + 128;            // (cg+4)*32 + hi4

#pragma unroll 1
  for (int j = 0; j < 32; ++j) {
    CLUSTER(hA0,hA1,hA2,hA3,lA0,lA1,lA2,lA3,cinA)
    if (j < 31) { LOADW(hA0,hA1,hA2,hA3,lA0,lA1,lA2,lA3,cinA,wpA,cpA) }
    TOURNP(acc0, 0, pbA)
    TOURNP(acc1, 1, pbA)
    pbA += 256;
    CLUSTER(hB0,hB1,hB2,hB3,lB0,lB1,lB2,lB3,cinB)
    if (j < 31) { LOADW(hB0,hB1,hB2,hB3,lB0,lB1,lB2,lB3,cinB,wpB,cpB) }
    TOURNP(acc0, 0, pbB)
    TOURNP(acc1, 1, pbB)
    pbB += 256;
  }

  // ---- merge the two hi-halves (disjoint code sets, same rows) ----
#pragma unroll
  for (int s = 0; s < 2; ++s) {
    const float od = __shfl_xor(bestd[s], 32, 64);
    const int   ok = __shfl_xor(bestk[s], 32, 64);
    if (od < bestd[s] || (od == bestd[s] && ok < bestk[s])) { bestd[s] = od; bestk[s] = ok; }
  }
  if (lane < 32) {
    md[(0*32 + r31)*4 + cg] = bestd[0];  mk[(0*32 + r31)*4 + cg] = bestk[0];
    md[(1*32 + r31)*4 + cg] = bestd[1];  mk[(1*32 + r31)*4 + cg] = bestk[1];
  }
  __syncthreads();

  if (t < 64) {
    const int row = t;
    float bd = md[row*4]; int bk = mk[row*4];
#pragma unroll
    for (int u2 = 1; u2 < 4; ++u2) {
      const float d2 = md[row*4 + u2]; const int k2 = mk[row*4 + u2];
      if (d2 < bd || (d2 == bd && k2 < bk)) { bd = d2; bk = k2; }
    }
    out[OUT_IDX + row0 + row] = (float)bk;
    ((int*)ws)[WS_IDX + row0 + row] = bk;
    bkL[row] = bk;
    atomicAdd(&ws[WS_COUNTS + bk], 1.0f);
  }
  __syncthreads();

  // ---- fused EMA segment-sum: 4 waves x 16 rows, lane = dim ----
#pragma unroll 4
  for (int r = 0; r < 16; ++r) {
    const int row = wv*16 + r;
    const int k = bkL[row];
    atomicAdd(&ws[WS_EMB + (size_t)k*64 + lane],
              xg[(size_t)(row0 + row)*64 + lane]);
  }
}

// stats: ONE block, no atomics
__global__ __launch_bounds__(256) void stats_kernel(const float* __restrict__ cc,
                                                    float* __restrict__ out,
                                                    float* __restrict__ ws) {
  const int t = threadIdx.x;
  float v1 = 0.0f, v2 = 0.0f;
#pragma unroll
  for (int i = 0; i < 32; ++i) {
    const int k = i*256 + t;
    const float cnt = ws[WS_COUNTS + k];
    const float ncc = __fadd_rn(__fmul_rn(DECAYF, cc[k]), __fmul_rn(OMDF, cnt));
    out[OUT_NCC + k] = ncc;
    const float p = cnt * (1.0f/32768.0f);
    v1 += ncc;
    v2 += __fmul_rn(p, logf(__fadd_rn(p, 1e-10f)));
  }
#pragma unroll
  for (int off = 32; off > 0; off >>= 1) {
    v1 += __shfl_down(v1, off);
    v2 += __shfl_down(v2, off);
  }
  __shared__ float s1[4], s2[4];
  const int lane = t & 63, wid = t >> 6;
  if (lane == 0) { s1[wid] = v1; s2[wid] = v2; }
  __syncthreads();
  if (t == 0) {
    ws[WS_N]   = (s1[0]+s1[1]) + (s1[2]+s1[3]);
    ws[WS_ENT] = (s2[0]+s2[1]) + (s2[2]+s2[3]);
  }
}

// fused update + quant: linear codebook update, then gather-quantize with
// on-the-fly recompute of new_weight rows (bit-identical arithmetic).
__global__ __launch_bounds__(256) void update_quant_kernel(const float* __restrict__ xg,
                                                           const float* __restrict__ ws0,
                                                           float* __restrict__ out,
                                                           float* __restrict__ ws) {
  const int t = threadIdx.x;
  const float n = ws[WS_N];
  const float den = __fadd_rn(n, 0.08192f);

  // ---- linear codebook update: one float4 per thread ----
  const int e4 = blockIdx.x * 256 + t;      // < 131072 float4s
  {
    const int k = e4 >> 4;
    const float ncc = out[OUT_NCC + k];
    const float smoothed = __fmul_rn(__fadd_rn(ncc, 1e-5f) / den, n);
    float4 w0 = *(const float4*)(ws0 + (size_t)e4*4);
    float4 em = *(const float4*)(ws + WS_EMB + (size_t)e4*4);
    float wv4[4] = {w0.x, w0.y, w0.z, w0.w};
    float ev4[4] = {em.x, em.y, em.z, em.w};
    float nwsv[4], nwv[4];
#pragma unroll
    for (int i = 0; i < 4; ++i) {
      nwsv[i] = __fadd_rn(__fmul_rn(DECAYF, wv4[i]), __fmul_rn(OMDF, ev4[i]));
      nwv[i]  = nwsv[i] / smoothed;         // exact division (reference: nws / smoothed)
    }
    float4 onws = {nwsv[0], nwsv[1], nwsv[2], nwsv[3]};
    float4 onw  = {nwv[0],  nwv[1],  nwv[2],  nwv[3]};
    *(float4*)(out + OUT_NWS + (size_t)e4*4) = onws;
    *(float4*)(out + OUT_NW  + (size_t)e4*4) = onw;
    if (e4 == 0) out[OUT_PERP] = expf(-ws[WS_ENT]);
  }

  // ---- quant + loss partials (per-block slot in WS_COUNTS, post-stats reuse) ----
  const int* idxb = (const int*)ws + WS_IDX;
  float v = 0.0f;
#pragma unroll
  for (int j = 0; j < 4; ++j) {
    const int qe4 = (j*512 + blockIdx.x)*256 + t;   // float4 index, coalesced
    const int row = qe4 >> 4, d = (qe4 & 15) * 4;
    const int k = idxb[row];
    const float ncc = out[OUT_NCC + k];
    const float smK = __fmul_rn(__fadd_rn(ncc, 1e-5f) / den, n);
    float4 wq = *(const float4*)(ws0 + (size_t)k*64 + d);
    float4 eq = *(const float4*)(ws + WS_EMB + (size_t)k*64 + d);
    float4 x  = *(const float4*)(xg + (size_t)qe4*4);
    float wv4[4] = {wq.x,wq.y,wq.z,wq.w};
    float ev4[4] = {eq.x,eq.y,eq.z,eq.w};
    float xv[4]  = {x.x,x.y,x.z,x.w};
    float4 o; float ov[4];
#pragma unroll
    for (int i = 0; i < 4; ++i) {
      const float nws = __fadd_rn(__fmul_rn(DECAYF, wv4[i]), __fmul_rn(OMDF, ev4[i]));
      const float q = nws / smK;            // == new_weight[k][d+i], identical rounding
      const float df = __fsub_rn(q, xv[i]);
      ov[i] = __fadd_rn(xv[i], df);
      v = fmaf(df, df, v);
    }
    o.x = ov[0]; o.y = ov[1]; o.z = ov[2]; o.w = ov[3];
    *(float4*)(out + OUT_Q + (size_t)qe4*4) = o;
  }
#pragma unroll
  for (int off = 32; off > 0; off >>= 1) v += __shfl_down(v, off);
  __shared__ float sm[4];
  const int lane = t & 63, wid = t >> 6;
  if (lane == 0) sm[wid] = v;
  __syncthreads();
  if (t == 0) ws[WS_COUNTS + blockIdx.x] = (sm[0]+sm[1]) + (sm[2]+sm[3]);
}

__global__ void final_kernel(float* __restrict__ out, const float* __restrict__ ws) {
  const int t = threadIdx.x;   // 64 threads
  float v = 0.0f;
#pragma unroll
  for (int i = 0; i < 8; ++i) v += ws[WS_COUNTS + i*64 + t];
#pragma unroll
  for (int off = 32; off > 0; off >>= 1) v += __shfl_down(v, off);
  if (t == 0) out[OUT_LOSS] = __fmul_rn(0.25f, v / 2097152.0f);
}

extern "C" void kernel_launch(void* const* d_in, const int* in_sizes, int n_in,
                              void* d_out, int out_size, void* d_ws, size_t ws_size,
                              hipStream_t stream) {
  (void)in_sizes; (void)n_in; (void)out_size; (void)ws_size;
  const float* x   = (const float*)d_in[0];
  const float* w   = (const float*)d_in[1];
  const float* cc  = (const float*)d_in[2];
  const float* ws0 = (const float*)d_in[3];
  float* out = (float*)d_out;
  float* ws  = (float*)d_ws;

  hipMemsetAsync(d_ws, 0, (size_t)WS_ZERO_UNITS * 4, stream);
  hipLaunchKernelGGL(prep_kernel,         dim3(288), dim3(256), 0, stream, w, ws);
  hipLaunchKernelGGL(argmin_kernel,       dim3(512), dim3(256), 0, stream, x, out, ws);
  hipLaunchKernelGGL(stats_kernel,        dim3(1),   dim3(256), 0, stream, cc, out, ws);
  hipLaunchKernelGGL(update_quant_kernel, dim3(512), dim3(256), 0, stream, x, ws0, out, ws);
  hipLaunchKernelGGL(final_kernel,        dim3(1),   dim3(64),  0, stream, out, ws);
}

// Round 7
// 177.789 us; speedup vs baseline: 1.1459x; 1.1459x over previous
//
#include <hip/hip_runtime.h>
#include <math.h>

typedef _Float16 f16x8 __attribute__((ext_vector_type(8)));
typedef float f32x4 __attribute__((ext_vector_type(4)));

// Problem constants
#define NROWS 32768   // 8*4096 input rows
#define KEMB  8192    // codebook entries
// DIM = 64

#define DECAYF 0.99f
#define OMDF   0.01f

// d_out layout (floats), reference return order
#define OUT_Q    0          // quantized, 2097152
#define OUT_LOSS 2097152    // vq_loss, 1
#define OUT_IDX  2097153    // idx (as float), 32768
#define OUT_PERP 2129921    // perplexity, 1
#define OUT_NW   2129922    // new_weight, 524288
#define OUT_NCC  2654210    // new_cc, 8192
#define OUT_NWS  2662402    // new_ws, 524288

// d_ws layout (4-byte units)
#define WS_N      0
#define WS_ENT    1
#define WS_COUNTS 4                    // 8192 floats (argmin atomics; reused as loss partials)
#define WS_EMB    8196                 // 524288 floats (atomic)
#define WS_IDX    532484               // 32768 ints
#define WS_W2H    565252               // 8192 floats (= ||w||^2 / 2)
#define WS_WFRAG  573444               // 524288 f32 units = 2 MB f16 frag image
#define WS_ZERO_UNITS 532484           // scalars+counts+emb

__device__ __forceinline__ float sq_rn(float v) { return __fmul_rn(v, v); }

// numpy pairwise_sum order for 64 contiguous squared values
__device__ __forceinline__ float npsumsq64(const float* vbuf) {
  float a[8];
#pragma unroll
  for (int j = 0; j < 8; ++j) a[j] = sq_rn(vbuf[j]);
#pragma unroll
  for (int m = 1; m < 8; ++m)
#pragma unroll
    for (int j = 0; j < 8; ++j) a[j] = __fadd_rn(a[j], sq_rn(vbuf[m*8 + j]));
  return __fadd_rn(__fadd_rn(__fadd_rn(a[0],a[1]), __fadd_rn(a[2],a[3])),
                   __fadd_rn(__fadd_rn(a[4],a[5]), __fadd_rn(a[6],a[7])));
}

// split a float into (hi, lo) fp16 pair; hi+lo reproduces x to ~22 bits
__device__ __forceinline__ void split_f16(float x, _Float16& hi, _Float16& lo) {
  hi = (_Float16)x;
  float r = __fsub_rn(x, (float)hi);   // exact (Sterbenz)
  lo = (_Float16)r;
}

// prep: w2h[k] = 0.5*||w_k||^2 (numpy order), W -> fragment-image f16 hi/lo.
// Image layout: frag(panel P, s, lane l) at wf[((P*4+s)*64+l)*8 .. +8];
// s=0,1 hi (K 0..31 / 32..63), s=2,3 lo. A per-lane dwordx4 load IS an MFMA frag.
__global__ __launch_bounds__(256) void prep_kernel(const float* __restrict__ wg,
                                                   float* __restrict__ ws) {
  const int tid = blockIdx.x * 256 + threadIdx.x;
  if (tid < KEMB) {
    const float* src = wg + (size_t)tid * 64;
    float vbuf[64];
#pragma unroll
    for (int f = 0; f < 16; ++f) {
      float4 v = *(const float4*)(src + f*4);
      vbuf[f*4+0]=v.x; vbuf[f*4+1]=v.y; vbuf[f*4+2]=v.z; vbuf[f*4+3]=v.w;
    }
    ws[WS_W2H + tid] = __fmul_rn(0.5f, npsumsq64(vbuf));
  } else if (tid < KEMB + 65536) {
    const int u = tid - KEMB;            // granule: code K, dims g*8..g*8+7
    const int K = u >> 3, g = u & 7;
    const int n = K & 15, P = K >> 4;    // global panel 0..511
    const int slot = (g&3)*16 + n, shi = g >> 2;
    const float* src = wg + (size_t)K*64 + g*8;
    float4 v0 = *(const float4*)src, v1 = *(const float4*)(src + 4);
    float vv[8] = {v0.x,v0.y,v0.z,v0.w,v1.x,v1.y,v1.z,v1.w};
    f16x8 hi, lo;
#pragma unroll
    for (int j = 0; j < 8; ++j) { _Float16 h, l; split_f16(vv[j], h, l); hi[j]=h; lo[j]=l; }
    _Float16* wf = (_Float16*)(ws + WS_WFRAG);
    *(f16x8*)&wf[((size_t)(P*4 + shi)*64 + slot)*8]     = hi;
    *(f16x8*)&wf[((size_t)(P*4 + 2 + shi)*64 + slot)*8] = lo;
  }
}

// one 16-code-panel MFMA cluster into ACC (C-in = CW = 0.5||w||^2, A = W frags,
// B = resident negated X frags) — distances bit-identical to prior versions.
#define MFMA_CLUSTER(ACC, H0, H1, L0, L1, CW)                                                 \
  __builtin_amdgcn_s_setprio(1);                                                              \
  _Pragma("unroll")                                                                           \
  for (int bt = 0; bt < 4; ++bt) ACC[bt] = __builtin_amdgcn_mfma_f32_16x16x32_f16(H0, b[bt][0], CW,      0,0,0); \
  _Pragma("unroll")                                                                           \
  for (int bt = 0; bt < 4; ++bt) ACC[bt] = __builtin_amdgcn_mfma_f32_16x16x32_f16(H1, b[bt][1], ACC[bt], 0,0,0); \
  _Pragma("unroll")                                                                           \
  for (int bt = 0; bt < 4; ++bt) ACC[bt] = __builtin_amdgcn_mfma_f32_16x16x32_f16(H0, b[bt][2], ACC[bt], 0,0,0); \
  _Pragma("unroll")                                                                           \
  for (int bt = 0; bt < 4; ++bt) ACC[bt] = __builtin_amdgcn_mfma_f32_16x16x32_f16(H1, b[bt][3], ACC[bt], 0,0,0); \
  _Pragma("unroll")                                                                           \
  for (int bt = 0; bt < 4; ++bt) ACC[bt] = __builtin_amdgcn_mfma_f32_16x16x32_f16(L0, b[bt][0], ACC[bt], 0,0,0); \
  _Pragma("unroll")                                                                           \
  for (int bt = 0; bt < 4; ++bt) ACC[bt] = __builtin_amdgcn_mfma_f32_16x16x32_f16(L1, b[bt][1], ACC[bt], 0,0,0); \
  __builtin_amdgcn_s_setprio(0);

// stream load of one panel into a named register set; pointer advances by
// 2 panels' stride (each set handles every other panel of this wave's slice)
#define LOADP(H0, H1, L0, L1, CW, WP, CP)           \
  H0 = *(const f16x8*)(WP);                         \
  H1 = *(const f16x8*)(WP + 512);                   \
  L0 = *(const f16x8*)(WP + 1024);                  \
  L1 = *(const f16x8*)(WP + 1536);                  \
  CW = *(const f32x4*)(CP);                         \
  WP += 16384; CP += 128;

// tournament, strict-compare form. Bit-identical to the verified descending
// scan: pm uses the same fminf tree; ties within a pair keep the lower reg
// (strict <), cross-pair tie keeps pair {0,1}; pm<bestd strict keeps the
// earlier (lower-k) panel. ~11 VALU/bt.
#define TOURN(ACC, C0)                                                       \
  _Pragma("unroll")                                                          \
  for (int bt = 0; bt < 4; ++bt) {                                           \
    const float d0 = ACC[bt][0], d1 = ACC[bt][1], d2 = ACC[bt][2], d3 = ACC[bt][3]; \
    const float m01 = fminf(d0, d1), m23 = fminf(d2, d3);                    \
    const float pm  = fminf(m01, m23);                                       \
    const int i01 = (d1 < d0) ? 1 : 0;                                       \
    const int i23 = (d3 < d2) ? 3 : 2;                                       \
    const int isel = (m23 < m01) ? i23 : i01;                                \
    if (pm < bestd[bt]) { bestd[bt] = pm; bestk[bt] = (C0) + isel; }         \
  }

// argmin v14 = r5 structure (best verified: 98.4us, bit-exact) + wave
// DE-PHASING. r5 counters: MfmaUtil 49 + VALUBusy 48 = 97%, idle ~0 -> the
// two co-resident waves are phase-locked (identical barrier-free loop,
// launched together): both do MFMA together (pipe serializes), both do
// tournament together (matrix pipe drains). m114: MFMA/VALU from DIFFERENT
// waves overlap fully -- but only at different phases. Seed a persistent
// 128-384cy offset via one-time s_sleep keyed on a block hash; loop has no
// barriers so the offset persists. setprio(1) around the cluster then gives
// the scheduler a role-split to arbitrate (T5 mechanism).
__global__ __launch_bounds__(256, 2) void argmin_kernel(const float* __restrict__ xg,
                                                        float* __restrict__ out,
                                                        float* __restrict__ ws) {
  __shared__ __align__(16) _Float16 xp[4*4*64*8];   // 16 KB, X frags (negated)
  __shared__ float md[64*4];
  __shared__ int   mk[64*4];
  __shared__ int   bkL[64];

  const int t    = threadIdx.x;
  const int lane = t & 63, wv = t >> 6;     // wv 0..3
  const int quad = lane >> 4, n16 = lane & 15;
  const int cg = wv;                        // code slice 0..3
  const int row0 = blockIdx.x * 64;
  const _Float16* __restrict__ wfrag = (const _Float16*)(ws + WS_WFRAG);
  const float* __restrict__ w2hg = ws + WS_W2H;

  // ---- prologue: convert X tile (NEGATED) into fragment layout ----
#pragma unroll
  for (int it = 0; it < 2; ++it) {
    const int u  = t + 256*it;              // < 512 granules (64 rows)
    const int rp = u >> 7, n = (u >> 3) & 15, g = u & 7;
    const float* src = xg + (size_t)(row0 + rp*16 + n)*64 + g*8;
    float4 v0 = *(const float4*)src, v1 = *(const float4*)(src + 4);
    float vv[8] = {v0.x,v0.y,v0.z,v0.w,v1.x,v1.y,v1.z,v1.w};
    f16x8 hi, lo;
#pragma unroll
    for (int j = 0; j < 8; ++j) { _Float16 h, l; split_f16(-vv[j], h, l); hi[j]=h; lo[j]=l; }
    const int slot = (g&3)*16 + n, shi = g >> 2;
    *(f16x8*)&xp[(((rp*4) + shi)*64 + slot)*8]     = hi;
    *(f16x8*)&xp[(((rp*4) + 2 + shi)*64 + slot)*8] = lo;
  }
  __syncthreads();

  // resident X frags (B operand): all 64 rows of this block, 4 tiles of 16
  f16x8 b[4][4];
#pragma unroll
  for (int bt = 0; bt < 4; ++bt)
#pragma unroll
    for (int s = 0; s < 4; ++s)
      b[bt][s] = *(const f16x8*)&xp[(((bt*4) + s)*64 + lane)*8];

  // ---- de-phase co-resident waves: one-time sleep, 0/128/256/384 cy.
  // Co-resident pairs on a SIMD are (same-wv, different-block) in the common
  // wv->SIMD mapping, so key on a block hash; sleep persists (no loop barriers).
  {
    const unsigned ph = (blockIdx.x * 2654435761u) >> 30;   // 0..3
    if (ph & 1) __builtin_amdgcn_s_sleep(2);
    if (ph & 2) __builtin_amdgcn_s_sleep(4);
  }

  float bestd[4]; int bestk[4];
#pragma unroll
  for (int i = 0; i < 4; ++i) { bestd[i] = INFINITY; bestk[i] = 0; }

  const int q4 = quad * 4;

  // W panel stream: this wave covers panels cg, cg+4, ..., cg+4*127.
  // setA sweeps even-m panels (stride 2*8192 halves), setB odd-m panels.
  const _Float16* wpA = wfrag + (size_t)cg * 2048 + (size_t)lane * 8;
  const _Float16* wpB = wpA + 8192;
  const float*    cpA = w2hg + cg*16 + q4;
  const float*    cpB = cpA + 64;

  f16x8 hA0, hA1, lA0, lA1, hB0, hB1, lB0, lB1;
  f32x4 cwA, cwB;

  LOADP(hA0, hA1, lA0, lA1, cwA, wpA, cpA);   // panel 0
  LOADP(hB0, hB1, lB0, lB1, cwB, wpB, cpB);   // panel 1

  f32x4 accA[4], accB[4];
  int c0A = cg*16 + q4;                       // panel 0 codes
  int c0B = c0A + 64;                         // panel 1 codes

  MFMA_CLUSTER(accA, hA0, hA1, lA0, lA1, cwA);   // panel 0
  LOADP(hA0, hA1, lA0, lA1, cwA, wpA, cpA);      // panel 2 (2-deep)

#pragma unroll 1
  for (int j = 0; j < 63; ++j) {
    MFMA_CLUSTER(accB, hB0, hB1, lB0, lB1, cwB); // panel 2j+1 (loaded 1 phase ago)
    LOADP(hB0, hB1, lB0, lB1, cwB, wpB, cpB);    // panel 2j+3
    TOURN(accA, c0A);                            // panel 2j
    MFMA_CLUSTER(accA, hA0, hA1, lA0, lA1, cwA); // panel 2j+2
    c0A += 128;
    if (j < 62) { LOADP(hA0, hA1, lA0, lA1, cwA, wpA, cpA); }  // panel 2j+4
    TOURN(accB, c0B);                            // panel 2j+1
    c0B += 128;
  }
  MFMA_CLUSTER(accB, hB0, hB1, lB0, lB1, cwB);   // panel 127
  TOURN(accA, c0A);                              // panel 126
  TOURN(accB, c0B);                              // panel 127

  // ---- merge across the 4 quads (same row, disjoint code slices) ----
#pragma unroll
  for (int bt = 0; bt < 4; ++bt) {
    float bd = bestd[bt]; int bk = bestk[bt];
#pragma unroll
    for (int m = 16; m < 64; m <<= 1) {
      const float od = __shfl_xor(bd, m, 64);
      const int   ok = __shfl_xor(bk, m, 64);
      if (od < bd || (od == bd && ok < bk)) { bd = od; bk = ok; }
    }
    if (lane < 16) {
      const int row = bt*16 + n16;
      md[row*4 + cg] = bd;
      mk[row*4 + cg] = bk;
    }
  }
  __syncthreads();

  if (t < 64) {
    const int row = t;
    float bd = md[row*4]; int bk = mk[row*4];
#pragma unroll
    for (int u2 = 1; u2 < 4; ++u2) {
      const float d2 = md[row*4 + u2]; const int k2 = mk[row*4 + u2];
      if (d2 < bd || (d2 == bd && k2 < bk)) { bd = d2; bk = k2; }
    }
    out[OUT_IDX + row0 + row] = (float)bk;
    ((int*)ws)[WS_IDX + row0 + row] = bk;
    bkL[row] = bk;
    atomicAdd(&ws[WS_COUNTS + bk], 1.0f);
  }
  __syncthreads();

  // ---- fused EMA segment-sum: 4 waves x 16 rows, lane = dim ----
#pragma unroll 4
  for (int r = 0; r < 16; ++r) {
    const int row = wv*16 + r;
    const int k = bkL[row];
    atomicAdd(&ws[WS_EMB + (size_t)k*64 + lane],
              xg[(size_t)(row0 + row)*64 + lane]);
  }
}

// stats: ONE block, no atomics
__global__ __launch_bounds__(256) void stats_kernel(const float* __restrict__ cc,
                                                    float* __restrict__ out,
                                                    float* __restrict__ ws) {
  const int t = threadIdx.x;
  float v1 = 0.0f, v2 = 0.0f;
#pragma unroll
  for (int i = 0; i < 32; ++i) {
    const int k = i*256 + t;
    const float cnt = ws[WS_COUNTS + k];
    const float ncc = __fadd_rn(__fmul_rn(DECAYF, cc[k]), __fmul_rn(OMDF, cnt));
    out[OUT_NCC + k] = ncc;
    const float p = cnt * (1.0f/32768.0f);
    v1 += ncc;
    v2 += __fmul_rn(p, logf(__fadd_rn(p, 1e-10f)));
  }
#pragma unroll
  for (int off = 32; off > 0; off >>= 1) {
    v1 += __shfl_down(v1, off);
    v2 += __shfl_down(v2, off);
  }
  __shared__ float s1[4], s2[4];
  const int lane = t & 63, wid = t >> 6;
  if (lane == 0) { s1[wid] = v1; s2[wid] = v2; }
  __syncthreads();
  if (t == 0) {
    ws[WS_N]   = (s1[0]+s1[1]) + (s1[2]+s1[3]);
    ws[WS_ENT] = (s2[0]+s2[1]) + (s2[2]+s2[3]);
  }
}

// fused update + quant: linear codebook update, then gather-quantize with
// on-the-fly recompute of new_weight rows (bit-identical arithmetic).
__global__ __launch_bounds__(256) void update_quant_kernel(const float* __restrict__ xg,
                                                           const float* __restrict__ ws0,
                                                           float* __restrict__ out,
                                                           float* __restrict__ ws) {
  const int t = threadIdx.x;
  const float n = ws[WS_N];
  const float den = __fadd_rn(n, 0.08192f);

  // ---- linear codebook update: one float4 per thread ----
  const int e4 = blockIdx.x * 256 + t;      // < 131072 float4s
  {
    const int k = e4 >> 4;
    const float ncc = out[OUT_NCC + k];
    const float smoothed = __fmul_rn(__fadd_rn(ncc, 1e-5f) / den, n);
    float4 w0 = *(const float4*)(ws0 + (size_t)e4*4);
    float4 em = *(const float4*)(ws + WS_EMB + (size_t)e4*4);
    float wv4[4] = {w0.x, w0.y, w0.z, w0.w};
    float ev4[4] = {em.x, em.y, em.z, em.w};
    float nwsv[4], nwv[4];
#pragma unroll
    for (int i = 0; i < 4; ++i) {
      nwsv[i] = __fadd_rn(__fmul_rn(DECAYF, wv4[i]), __fmul_rn(OMDF, ev4[i]));
      nwv[i]  = nwsv[i] / smoothed;         // exact division (reference: nws / smoothed)
    }
    float4 onws = {nwsv[0], nwsv[1], nwsv[2], nwsv[3]};
    float4 onw  = {nwv[0],  nwv[1],  nwv[2],  nwv[3]};
    *(float4*)(out + OUT_NWS + (size_t)e4*4) = onws;
    *(float4*)(out + OUT_NW  + (size_t)e4*4) = onw;
    if (e4 == 0) out[OUT_PERP] = expf(-ws[WS_ENT]);
  }

  // ---- quant + loss partials (per-block slot in WS_COUNTS, post-stats reuse) ----
  const int* idxb = (const int*)ws + WS_IDX;
  float v = 0.0f;
#pragma unroll
  for (int j = 0; j < 4; ++j) {
    const int qe4 = (j*512 + blockIdx.x)*256 + t;   // float4 index, coalesced
    const int row = qe4 >> 4, d = (qe4 & 15) * 4;
    const int k = idxb[row];
    const float ncc = out[OUT_NCC + k];
    const float smK = __fmul_rn(__fadd_rn(ncc, 1e-5f) / den, n);
    float4 wq = *(const float4*)(ws0 + (size_t)k*64 + d);
    float4 eq = *(const float4*)(ws + WS_EMB + (size_t)k*64 + d);
    float4 x  = *(const float4*)(xg + (size_t)qe4*4);
    float wv4[4] = {wq.x,wq.y,wq.z,wq.w};
    float ev4[4] = {eq.x,eq.y,eq.z,eq.w};
    float xv[4]  = {x.x,x.y,x.z,x.w};
    float4 o; float ov[4];
#pragma unroll
    for (int i = 0; i < 4; ++i) {
      const float nws = __fadd_rn(__fmul_rn(DECAYF, wv4[i]), __fmul_rn(OMDF, ev4[i]));
      const float q = nws / smK;            // == new_weight[k][d+i], identical rounding
      const float df = __fsub_rn(q, xv[i]);
      ov[i] = __fadd_rn(xv[i], df);
      v = fmaf(df, df, v);
    }
    o.x = ov[0]; o.y = ov[1]; o.z = ov[2]; o.w = ov[3];
    *(float4*)(out + OUT_Q + (size_t)qe4*4) = o;
  }
#pragma unroll
  for (int off = 32; off > 0; off >>= 1) v += __shfl_down(v, off);
  __shared__ float sm[4];
  const int lane = t & 63, wid = t >> 6;
  if (lane == 0) sm[wid] = v;
  __syncthreads();
  if (t == 0) ws[WS_COUNTS + blockIdx.x] = (sm[0]+sm[1]) + (sm[2]+sm[3]);
}

__global__ void final_kernel(float* __restrict__ out, const float* __restrict__ ws) {
  const int t = threadIdx.x;   // 64 threads
  float v = 0.0f;
#pragma unroll
  for (int i = 0; i < 8; ++i) v += ws[WS_COUNTS + i*64 + t];
#pragma unroll
  for (int off = 32; off > 0; off >>= 1) v += __shfl_down(v, off);
  if (t == 0) out[OUT_LOSS] = __fmul_rn(0.25f, v / 2097152.0f);
}

extern "C" void kernel_launch(void* const* d_in, const int* in_sizes, int n_in,
                              void* d_out, int out_size, void* d_ws, size_t ws_size,
                              hipStream_t stream) {
  (void)in_sizes; (void)n_in; (void)out_size; (void)ws_size;
  const float* x   = (const float*)d_in[0];
  const float* w   = (const float*)d_in[1];
  const float* cc  = (const float*)d_in[2];
  const float* ws0 = (const float*)d_in[3];
  float* out = (float*)d_out;
  float* ws  = (float*)d_ws;

  hipMemsetAsync(d_ws, 0, (size_t)WS_ZERO_UNITS * 4, stream);
  hipLaunchKernelGGL(prep_kernel,         dim3(288), dim3(256), 0, stream, w, ws);
  hipLaunchKernelGGL(argmin_kernel,       dim3(512), dim3(256), 0, stream, x, out, ws);
  hipLaunchKernelGGL(stats_kernel,        dim3(1),   dim3(256), 0, stream, cc, out, ws);
  hipLaunchKernelGGL(update_quant_kernel, dim3(512), dim3(256), 0, stream, x, ws0, out, ws);
  hipLaunchKernelGGL(final_kernel,        dim3(1),   dim3(64),  0, stream, out, ws);
}